// Round 14
// baseline (173.728 us; speedup 1.0000x reference)
//
#include <hip/hip_runtime.h>
#include <stdint.h>
#include <math.h>

typedef float  f32x2  __attribute__((ext_vector_type(2)));
typedef float  f32x4  __attribute__((ext_vector_type(4)));
typedef float  f32x16 __attribute__((ext_vector_type(16)));
typedef short  bf16x8 __attribute__((ext_vector_type(8)));
typedef unsigned int u32;
typedef unsigned int u32x4 __attribute__((ext_vector_type(4)));
typedef unsigned short ushort_t;

#define MFMA32(a, b, c) __builtin_amdgcn_mfma_f32_32x32x16_bf16((a), (b), (c), 0, 0, 0)

constexpr int B_ = 8, C_ = 128, N_ = 4096;
constexpr float LOG2E = 1.44269504088896340736f;

__device__ __forceinline__ u32 pack2bf(float a, float b) {  // RNE, a->lo16 b->hi16
  u32 ua = __builtin_bit_cast(u32, a);
  u32 ub = __builtin_bit_cast(u32, b);
  ua += 0x7fffu + ((ua >> 16) & 1u);
  ub += 0x7fffu + ((ub >> 16) & 1u);
  return (ua >> 16) | (ub & 0xffff0000u);
}
__device__ __forceinline__ u32 pkfast(float a, float b) {   // round-half-up, 3 ops
  u32 ua = __builtin_bit_cast(u32, a) + 0x8000u;
  u32 ub = __builtin_bit_cast(u32, b) + 0x8000u;
  return __builtin_amdgcn_perm(ub, ua, 0x07060302u);        // [b_hi16 : a_hi16]
}
__device__ __forceinline__ bf16x8 pack8(const float* v, float s) {
  u32x4 d = { pack2bf(v[0]*s, v[1]*s), pack2bf(v[2]*s, v[3]*s),
              pack2bf(v[4]*s, v[5]*s), pack2bf(v[6]*s, v[7]*s) };
  return __builtin_bit_cast(bf16x8, d);
}

// async global -> LDS, 16B per lane; lds dst is wave-uniform base (+lane*16 by HW)
__device__ __forceinline__ void gload_lds16(const ushort_t* g, ushort_t* l) {
  __builtin_amdgcn_global_load_lds(
      (const __attribute__((address_space(1))) void*)g,
      (__attribute__((address_space(3))) void*)l, 16, 0, 0);
}

// exp2 + bf16 pack + cross-half exchange via v_permlane32_swap (verified R13).
__device__ __forceinline__ bf16x8 mk_pa(const f32x16& sv, int rb, float& lacc) {
  float e0 = __builtin_amdgcn_exp2f(sv[rb+0]);
  float e1 = __builtin_amdgcn_exp2f(sv[rb+1]);
  float e2 = __builtin_amdgcn_exp2f(sv[rb+2]);
  float e3 = __builtin_amdgcn_exp2f(sv[rb+3]);
  float e4 = __builtin_amdgcn_exp2f(sv[rb+4]);
  float e5 = __builtin_amdgcn_exp2f(sv[rb+5]);
  float e6 = __builtin_amdgcn_exp2f(sv[rb+6]);
  float e7 = __builtin_amdgcn_exp2f(sv[rb+7]);
  lacc += ((e0+e1)+(e2+e3)) + ((e4+e5)+(e6+e7));
  u32 a  = pkfast(e0, e1), b2 = pkfast(e2, e3);
  u32 c2 = pkfast(e4, e5), d2 = pkfast(e6, e7);
  asm("v_permlane32_swap_b32 %0, %1" : "+v"(a), "+v"(c2));
  asm("v_permlane32_swap_b32 %0, %1" : "+v"(b2), "+v"(d2));
  u32x4 fr = { a, b2, c2, d2 };
  return __builtin_bit_cast(bf16x8, fr);
}

// ---------------------------------------------------------------------------
// W prep: fp32 [d][c] -> bf16 fragment-linear Wf[widx][dt(4)][kc(8)][lane(64)][8]
// ---------------------------------------------------------------------------
__global__ __launch_bounds__(256)
void wprep_kernel(const float* __restrict__ Wq, const float* __restrict__ Wk,
                  const float* __restrict__ Wv, ushort_t* __restrict__ Wf)
{
  const int tid  = blockIdx.x * 256 + threadIdx.x;     // 0..6143
  const int widx = tid >> 11;
  const int r    = tid & 2047;
  const int dt   = r >> 9;
  const int kc   = (r >> 6) & 7;
  const int ln   = r & 63;
  const float* W = (widx == 0) ? Wq : (widx == 1) ? Wk : Wv;
  const float s  = (widx == 0) ? LOG2E : 1.0f;
  const int d    = dt * 32 + (ln & 31);
  const int c0   = kc * 16 + (ln >> 5) * 8;
  const float* p = W + d * C_ + c0;
  f32x4 lo = *(const f32x4*)p, hi = *(const f32x4*)(p + 4);
  float v[8] = { lo.x, lo.y, lo.z, lo.w, hi.x, hi.y, hi.z, hi.w };
  *(bf16x8*)(Wf + (size_t)tid * 8) = pack8(v, s);
}

// ---------------------------------------------------------------------------
// Projection, R20: R13 transposed-xs body, launch_bounds(256,4).
// proj is latency/L2-bound (24x1KB Wf L2-loads per wave, ~600 VALU/thread,
// 16.6KB LDS). (256,3) let the allocator use up to ~170 VGPR -> 12 waves/CU;
// register arithmetic fits 128 (xf 32 + sq/sk/sv 48 + W 12 + addr ~25), so
// force 4 waves/SIMD = 16 waves/CU. Output layouts unchanged (proven):
//  Qf/Kf: [b][i32(128)][kc(8)][lane(64)][8]
//  Vf   : [b][j64(64)][ct(4)][cc(4)][lane(64)][8]
// ---------------------------------------------------------------------------
__global__ __launch_bounds__(256, 4)
void proj_kernel(const float* __restrict__ x,
                 const float* __restrict__ bq, const float* __restrict__ bk,
                 const float* __restrict__ bv, const ushort_t* __restrict__ Wf,
                 ushort_t* __restrict__ Qf, ushort_t* __restrict__ Kf,
                 ushort_t* __restrict__ Vf)
{
  const int b   = blockIdx.x & 7;
  const int nt  = blockIdx.x >> 3;        // 32-pixel group, 0..127
  const int n0  = nt << 5;
  const int t   = threadIdx.x;
  const int dt  = t >> 6;                 // wave id = dt slice
  const int lane = t & 63;
  const int l31 = t & 31;
  const int lq1 = (t >> 5) & 1;

  __shared__ float xs[32 * 130];          // 16.6 KB, transposed [pix][c]
  {
    const float* xb = x + (size_t)b * C_ * N_ + n0;
    const int m  = t & 7;                 // pixel quad
    const int cb = t >> 3;                // c-row 0..31 per pass
#pragma unroll
    for (int it = 0; it < 4; ++it) {
      const int c = it * 32 + cb;
      f32x4 v = *(const f32x4*)(xb + (size_t)c * N_ + m * 4);
#pragma unroll
      for (int e = 0; e < 4; ++e)
        xs[(m * 4 + e) * 130 + c] = v[e];
    }
  }
  __syncthreads();

  // x fragment: lane l31 = pixel, lq1 = k-half; 8 consecutive c per kc.
  bf16x8 xf[8];
#pragma unroll
  for (int kc = 0; kc < 8; ++kc) {
    const float* row = &xs[l31 * 130 + kc * 16 + lq1 * 8];
    float v[8];
#pragma unroll
    for (int u = 0; u < 4; ++u) {
      f32x2 p = *(const f32x2*)(row + 2 * u);
      v[2*u] = p.x; v[2*u+1] = p.y;
    }
    xf[kc] = pack8(v, 1.0f);
  }

  const ushort_t* WQf = Wf;
  const ushort_t* WKf = Wf + 16384;
  const ushort_t* WVf = Wf + 32768;
  const f32x16 Z = {0,0,0,0,0,0,0,0,0,0,0,0,0,0,0,0};

  f32x16 sq = Z, sk = Z, sv = Z;
#pragma unroll
  for (int kc = 0; kc < 8; ++kc) {
    const size_t wo = (size_t)(dt * 8 + kc) * 512 + lane * 8;
    bf16x8 wq = *(const bf16x8*)(WQf + wo);
    bf16x8 wk = *(const bf16x8*)(WKf + wo);
    bf16x8 wvv = *(const bf16x8*)(WVf + wo);
    sq = MFMA32(wq, xf[kc], sq);     // D[m=d][n=pix]
    sk = MFMA32(wk, xf[kc], sk);
    sv = MFMA32(xf[kc], wvv, sv);    // D[m=pix][n=d]
  }

  // ---- Q/K stores (fragment-linear) ----
#pragma unroll
  for (int q = 0; q < 4; ++q) {
    const int dbase = dt * 32 + q * 8 + lq1 * 4;
    f32x4 b4q = *(const f32x4*)(bq + dbase);
    f32x4 b4k = *(const f32x4*)(bk + dbase);
    uint2 qs, ks;
    qs.x = pack2bf(sq[4*q+0] + b4q.x * LOG2E, sq[4*q+1] + b4q.y * LOG2E);
    qs.y = pack2bf(sq[4*q+2] + b4q.z * LOG2E, sq[4*q+3] + b4q.w * LOG2E);
    ks.x = pack2bf(sk[4*q+0] + b4k.x, sk[4*q+1] + b4k.y);
    ks.y = pack2bf(sk[4*q+2] + b4k.z, sk[4*q+3] + b4k.w);
    const int kcf = dt * 2 + (q >> 1), h = q & 1;
    const size_t off = ((size_t)((b * 128 + nt) * 8 + kcf) * 64 + h * 32 + l31) * 8 + lq1 * 4;
    *(uint2*)(Qf + off) = qs;
    *(uint2*)(Kf + off) = ks;
  }

  // ---- V stores ----
  {
    const float bvl = bv[dt * 32 + l31];           // lane = d
    const int j64 = nt >> 1, qp = nt & 1;
#pragma unroll
    for (int q = 0; q < 4; ++q) {
      uint2 vs;
      vs.x = pack2bf(sv[4*q+0] + bvl, sv[4*q+1] + bvl);
      vs.y = pack2bf(sv[4*q+2] + bvl, sv[4*q+3] + bvl);
      const int cc = qp * 2 + (q >> 1);
      const size_t off = ((size_t)((b * 64 + j64) * 4 + dt) * 4 + cc) * 512 +
                         (size_t)((q & 1) * 32 + l31) * 8 + lq1 * 4;
      *(uint2*)(Vf + off) = vs;
    }
  }
}

// ---------------------------------------------------------------------------
// Flash attention, R20 = R19 verbatim (session-best total: 165.8us).
// R13 loop (3-buffer, per-tile counted vmcnt(4), symmetric staging, setprio,
// permlane softmax) at js=2 (one opart slice, WRITE 33MB, cheapest combine).
// Structural plateau documented: MFMA issue rate pinned ~0.044/CU-cyc across
// 8 falsified structural theories; escaping needs the full co-designed
// multi-phase rewrite (grafts regress).
// ---------------------------------------------------------------------------
__global__ __launch_bounds__(256, 3)
void flash_kernel(const ushort_t* __restrict__ Qf, const ushort_t* __restrict__ Kf,
                  const ushort_t* __restrict__ Vf, float* __restrict__ out,
                  float* __restrict__ opart, float* __restrict__ lpart, int js)
{
  const int b     = blockIdx.x & 7;
  const int itile = (blockIdx.x >> 3) & 31;
  const int jsl   = blockIdx.x >> 8;
  const int t     = threadIdx.x;
  const int wv    = t >> 6;
  const int lane  = t & 63;
  const int l31   = t & 31;
  const int lq1   = (t >> 5) & 1;
  const int i0    = itile * 128 + wv * 32;

  __shared__ __align__(16) short smem[24576];   // 48 KB: 3xK(8KB) + 3xV(8KB)

  const int jt0 = (jsl * 128) / js;
  const int jt1 = ((jsl + 1) * 128) / js;
  const int NT  = jt1 - jt0;
  const ushort_t* Kt0   = Kf + (size_t)b * 524288;
  const ushort_t* Vbase = Vf + (size_t)b * 524288;

  // Stage K(jt)+V(jt) into buffer p. Every wave: 2 K-chunks + 2 V-chunks
  // (4 x 1KB DMA) -> uniform vmcnt accounting across waves.
  auto stage = [&](int jt, int p) {
    ushort_t* kb = (ushort_t*)smem + p * 4096;
    ushort_t* vb = (ushort_t*)smem + 12288 + p * 4096;
    const ushort_t* ksrc = Kt0 + (size_t)jt * 4096;
    const int qp = jt & 1;
    const ushort_t* vsrc = Vbase + (size_t)(jt >> 1) * 8192;
#pragma unroll
    for (int c = 0; c < 2; ++c) {
      const int g = wv * 2 + c;
      gload_lds16(ksrc + g * 512 + lane * 8, kb + g * 512);
    }
#pragma unroll
    for (int c = 0; c < 2; ++c) {
      const int h2 = wv * 2 + c;
      const int ct = h2 >> 1, h = h2 & 1;
      gload_lds16(vsrc + (size_t)(ct * 4 + qp * 2 + h) * 512 + lane * 8,
                  vb + h2 * 512);
    }
  };

  // Q fragments (persistent, coalesced): i32-group = itile*4 + wv
  bf16x8 qf[8];
  const size_t qb = (size_t)((b * 128 + itile * 4 + wv) * 8) * 512;
#pragma unroll
  for (int kc = 0; kc < 8; ++kc)
    qf[kc] = *(const bf16x8*)(Qf + qb + (size_t)kc * 512 + lane * 8);

  const f32x16 Z = {0,0,0,0,0,0,0,0,0,0,0,0,0,0,0,0};
  f32x16 o[4] = {Z, Z, Z, Z};
  float lsum = 0.f;

  auto qk = [&](const short* kbuf) -> f32x16 {
    f32x16 s = Z;
#pragma unroll
    for (int kc = 0; kc < 8; ++kc) {
      bf16x8 kfr = *(const bf16x8*)&kbuf[kc * 512 + lane * 8];
      s = MFMA32(kfr, qf[kc], s);
    }
    return s;
  };
  auto pv = [&](const short* vbuf, bf16x8 a0, bf16x8 a1) {
#pragma unroll
    for (int ct = 0; ct < 4; ++ct) {
      bf16x8 vf0 = *(const bf16x8*)&vbuf[(ct * 2 + 0) * 512 + lane * 8];
      o[ct] = MFMA32(vf0, a0, o[ct]);
      bf16x8 vf1 = *(const bf16x8*)&vbuf[(ct * 2 + 1) * 512 + lane * 8];
      o[ct] = MFMA32(vf1, a1, o[ct]);
    }
  };

  // ---- prologue: tiles 0,1 in flight; wait only tile 0 (vmcnt(4)) ----
  stage(jt0, 0);
  stage(jt0 + 1, 1);
  asm volatile("s_waitcnt vmcnt(4)" ::: "memory");   // qf + tile0 done; tile1 in flight
  __builtin_amdgcn_sched_barrier(0);
  __builtin_amdgcn_s_barrier();
  __builtin_amdgcn_sched_barrier(0);

  int pcur = 0, pstage = 2;
  for (int n = 0; n < NT; ++n) {
    if (n + 2 < NT) stage(jt0 + n + 2, pstage);      // into buf holding tile n-1
    pstage = (pstage == 2) ? 0 : pstage + 1;
    const short* kb = smem + pcur * 4096;
    const short* vb = smem + 12288 + pcur * 4096;
    pcur = (pcur == 2) ? 0 : pcur + 1;

    __builtin_amdgcn_s_setprio(1);
    f32x16 s = qk(kb);                               // S^T(n) = K*Q
    __builtin_amdgcn_s_setprio(0);
    bf16x8 pa0 = mk_pa(s, 0, lsum);                  // softmax (exp2 domain)
    bf16x8 pa1 = mk_pa(s, 8, lsum);
    __builtin_amdgcn_s_setprio(1);
    pv(vb, pa0, pa1);                                // PV(n)
    __builtin_amdgcn_s_setprio(0);

    if (n + 1 < NT) {
      if (n + 2 < NT) asm volatile("s_waitcnt vmcnt(4)" ::: "memory");  // tile n+1 ready
      else            asm volatile("s_waitcnt vmcnt(0)" ::: "memory");  // tail
      __builtin_amdgcn_sched_barrier(0);
      __builtin_amdgcn_s_barrier();
      __builtin_amdgcn_sched_barrier(0);
    }
  }

  lsum += __shfl_xor(lsum, 32);   // full row sum; lane l31 -> i = i0 + l31
  const int ib = i0 + l31;

  if (js == 1) {
    const float inv = 1.0f / lsum;
#pragma unroll
    for (int ct = 0; ct < 4; ++ct)
#pragma unroll
      for (int rg = 0; rg < 16; ++rg) {
        const int c = ct * 32 + (rg >> 2) * 8 + lq1 * 4 + (rg & 3);
        out[(size_t)(b * C_ + c) * N_ + ib] = o[ct][rg] * inv;
      }
  } else {
    float* op = jsl ? (opart + (size_t)(jsl - 1) * B_ * C_ * N_) : out;
#pragma unroll
    for (int ct = 0; ct < 4; ++ct)
#pragma unroll
      for (int rg = 0; rg < 16; ++rg) {
        const int c = ct * 32 + (rg >> 2) * 8 + lq1 * 4 + (rg & 3);
        op[(size_t)(b * C_ + c) * N_ + ib] = o[ct][rg];
      }
    if (lane < 32)
      lpart[(size_t)jsl * B_ * N_ + (size_t)b * N_ + ib] = lsum;
  }
}

// ---------------------------------------------------------------------------
// Combine: slice 0 lives in `out` (aliased); sums + normalizes in place.
// ---------------------------------------------------------------------------
__global__ __launch_bounds__(256)
void combine_kernel(const float* __restrict__ opart, const float* __restrict__ lpart,
                    float* __restrict__ out, int js)
{
  const int t  = blockIdx.x * 256 + threadIdx.x;
  const int n4 = (t & 1023) * 4;
  const int bc = t >> 10;
  const int b  = bc >> 7;
  const size_t off  = (size_t)bc * N_ + n4;
  const size_t loff = (size_t)b * N_ + n4;
  f32x4 os = *(const f32x4*)(out + off);
  f32x4 ls = *(const f32x4*)(lpart + loff);
  for (int s = 1; s < js; ++s) {
    os += *(const f32x4*)(opart + (size_t)(s - 1) * B_ * C_ * N_ + off);
    ls += *(const f32x4*)(lpart + (size_t)s * B_ * N_ + loff);
  }
  f32x4 r = { os.x / ls.x, os.y / ls.y, os.z / ls.z, os.w / ls.w };
  *(f32x4*)(out + off) = r;
}

// ---------------------------------------------------------------------------
extern "C" void kernel_launch(void* const* d_in, const int* in_sizes, int n_in,
                              void* d_out, int out_size, void* d_ws, size_t ws_size,
                              hipStream_t stream) {
  const float* x  = (const float*)d_in[0];
  const float* Wq = (const float*)d_in[1];
  const float* bq = (const float*)d_in[2];
  const float* Wk = (const float*)d_in[3];
  const float* bk = (const float*)d_in[4];
  const float* Wv = (const float*)d_in[5];
  const float* bv = (const float*)d_in[6];
  float* out = (float*)d_out;

  const size_t nc = (size_t)B_ * N_ * C_;
  ushort_t* qf = (ushort_t*)d_ws;
  ushort_t* kf = qf + nc;
  ushort_t* vf = kf + nc;
  ushort_t* wf = vf + nc;                          // 49152 elems
  const size_t base = (3 * nc + 49152) * sizeof(ushort_t);

  auto need = [&](int jss) {
    return base + (size_t)jss * (size_t)B_ * N_ * 4 +
           (size_t)(jss - 1) * (size_t)B_ * C_ * N_ * 4;   // slice0 = d_out
  };
  // js=2 (proven best slice count: one opart slice, WRITE 33MB).
  const int js = (ws_size >= need(2)) ? 2 : 1;

  float* lpart = (float*)((char*)d_ws + base);
  float* opart = lpart + (size_t)js * B_ * N_;

  hipLaunchKernelGGL(wprep_kernel, dim3(24), dim3(256), 0, stream, Wq, Wk, Wv, wf);
  hipLaunchKernelGGL(proj_kernel, dim3(1024), dim3(256), 0, stream,
                     x, bq, bk, bv, wf, qf, kf, vf);
  hipLaunchKernelGGL(flash_kernel, dim3(256 * js), dim3(256), 0, stream,
                     qf, kf, vf, out, opart, lpart, js);
  if (js > 1)
    hipLaunchKernelGGL(combine_kernel, dim3(4096), dim3(256), 0, stream,
                       opart, lpart, out, js);
}

// Round 15
// 165.415 us; speedup vs baseline: 1.0503x; 1.0503x over previous
//
#include <hip/hip_runtime.h>
#include <stdint.h>
#include <math.h>

typedef float  f32x2  __attribute__((ext_vector_type(2)));
typedef float  f32x4  __attribute__((ext_vector_type(4)));
typedef float  f32x16 __attribute__((ext_vector_type(16)));
typedef short  bf16x8 __attribute__((ext_vector_type(8)));
typedef unsigned int u32;
typedef unsigned int u32x4 __attribute__((ext_vector_type(4)));
typedef unsigned short ushort_t;

#define MFMA32(a, b, c) __builtin_amdgcn_mfma_f32_32x32x16_bf16((a), (b), (c), 0, 0, 0)

constexpr int B_ = 8, C_ = 128, N_ = 4096;
constexpr float LOG2E = 1.44269504088896340736f;

__device__ __forceinline__ u32 pack2bf(float a, float b) {  // RNE, a->lo16 b->hi16
  u32 ua = __builtin_bit_cast(u32, a);
  u32 ub = __builtin_bit_cast(u32, b);
  ua += 0x7fffu + ((ua >> 16) & 1u);
  ub += 0x7fffu + ((ub >> 16) & 1u);
  return (ua >> 16) | (ub & 0xffff0000u);
}
__device__ __forceinline__ u32 pkfast(float a, float b) {   // round-half-up, 3 ops
  u32 ua = __builtin_bit_cast(u32, a) + 0x8000u;
  u32 ub = __builtin_bit_cast(u32, b) + 0x8000u;
  return __builtin_amdgcn_perm(ub, ua, 0x07060302u);        // [b_hi16 : a_hi16]
}
__device__ __forceinline__ bf16x8 pack8(const float* v, float s) {
  u32x4 d = { pack2bf(v[0]*s, v[1]*s), pack2bf(v[2]*s, v[3]*s),
              pack2bf(v[4]*s, v[5]*s), pack2bf(v[6]*s, v[7]*s) };
  return __builtin_bit_cast(bf16x8, d);
}

// async global -> LDS, 16B per lane; lds dst is wave-uniform base (+lane*16 by HW)
__device__ __forceinline__ void gload_lds16(const ushort_t* g, ushort_t* l) {
  __builtin_amdgcn_global_load_lds(
      (const __attribute__((address_space(1))) void*)g,
      (__attribute__((address_space(3))) void*)l, 16, 0, 0);
}

// exp2 + bf16 pack + cross-half exchange via v_permlane32_swap (verified R13).
__device__ __forceinline__ bf16x8 mk_pa(const f32x16& sv, int rb, float& lacc) {
  float e0 = __builtin_amdgcn_exp2f(sv[rb+0]);
  float e1 = __builtin_amdgcn_exp2f(sv[rb+1]);
  float e2 = __builtin_amdgcn_exp2f(sv[rb+2]);
  float e3 = __builtin_amdgcn_exp2f(sv[rb+3]);
  float e4 = __builtin_amdgcn_exp2f(sv[rb+4]);
  float e5 = __builtin_amdgcn_exp2f(sv[rb+5]);
  float e6 = __builtin_amdgcn_exp2f(sv[rb+6]);
  float e7 = __builtin_amdgcn_exp2f(sv[rb+7]);
  lacc += ((e0+e1)+(e2+e3)) + ((e4+e5)+(e6+e7));
  u32 a  = pkfast(e0, e1), b2 = pkfast(e2, e3);
  u32 c2 = pkfast(e4, e5), d2 = pkfast(e6, e7);
  asm("v_permlane32_swap_b32 %0, %1" : "+v"(a), "+v"(c2));
  asm("v_permlane32_swap_b32 %0, %1" : "+v"(b2), "+v"(d2));
  u32x4 fr = { a, b2, c2, d2 };
  return __builtin_bit_cast(bf16x8, fr);
}

// ---------------------------------------------------------------------------
// W prep: fp32 [d][c] -> bf16 fragment-linear Wf[widx][dt(4)][kc(8)][lane(64)][8]
// ---------------------------------------------------------------------------
__global__ __launch_bounds__(256)
void wprep_kernel(const float* __restrict__ Wq, const float* __restrict__ Wk,
                  const float* __restrict__ Wv, ushort_t* __restrict__ Wf)
{
  const int tid  = blockIdx.x * 256 + threadIdx.x;     // 0..6143
  const int widx = tid >> 11;
  const int r    = tid & 2047;
  const int dt   = r >> 9;
  const int kc   = (r >> 6) & 7;
  const int ln   = r & 63;
  const float* W = (widx == 0) ? Wq : (widx == 1) ? Wk : Wv;
  const float s  = (widx == 0) ? LOG2E : 1.0f;
  const int d    = dt * 32 + (ln & 31);
  const int c0   = kc * 16 + (ln >> 5) * 8;
  const float* p = W + d * C_ + c0;
  f32x4 lo = *(const f32x4*)p, hi = *(const f32x4*)(p + 4);
  float v[8] = { lo.x, lo.y, lo.z, lo.w, hi.x, hi.y, hi.z, hi.w };
  *(bf16x8*)(Wf + (size_t)tid * 8) = pack8(v, s);
}

// ---------------------------------------------------------------------------
// Projection (R13 transposed-xs version at (256,3) -- R20's (256,4) spilled
// and cost ~8us; reverted):
//  Qf/Kf: [b][i32(128)][kc(8)][lane(64)][8]
//  Vf   : [b][j64(64)][ct(4)][cc(4)][lane(64)][8]
// ---------------------------------------------------------------------------
__global__ __launch_bounds__(256, 3)
void proj_kernel(const float* __restrict__ x,
                 const float* __restrict__ bq, const float* __restrict__ bk,
                 const float* __restrict__ bv, const ushort_t* __restrict__ Wf,
                 ushort_t* __restrict__ Qf, ushort_t* __restrict__ Kf,
                 ushort_t* __restrict__ Vf)
{
  const int b   = blockIdx.x & 7;
  const int nt  = blockIdx.x >> 3;        // 32-pixel group, 0..127
  const int n0  = nt << 5;
  const int t   = threadIdx.x;
  const int dt  = t >> 6;                 // wave id = dt slice
  const int lane = t & 63;
  const int l31 = t & 31;
  const int lq1 = (t >> 5) & 1;

  __shared__ float xs[32 * 130];          // 16.6 KB, transposed [pix][c]
  {
    const float* xb = x + (size_t)b * C_ * N_ + n0;
    const int m  = t & 7;                 // pixel quad
    const int cb = t >> 3;                // c-row 0..31 per pass
#pragma unroll
    for (int it = 0; it < 4; ++it) {
      const int c = it * 32 + cb;
      f32x4 v = *(const f32x4*)(xb + (size_t)c * N_ + m * 4);
#pragma unroll
      for (int e = 0; e < 4; ++e)
        xs[(m * 4 + e) * 130 + c] = v[e];
    }
  }
  __syncthreads();

  // x fragment: lane l31 = pixel, lq1 = k-half; 8 consecutive c per kc.
  bf16x8 xf[8];
#pragma unroll
  for (int kc = 0; kc < 8; ++kc) {
    const float* row = &xs[l31 * 130 + kc * 16 + lq1 * 8];
    float v[8];
#pragma unroll
    for (int u = 0; u < 4; ++u) {
      f32x2 p = *(const f32x2*)(row + 2 * u);
      v[2*u] = p.x; v[2*u+1] = p.y;
    }
    xf[kc] = pack8(v, 1.0f);
  }

  const ushort_t* WQf = Wf;
  const ushort_t* WKf = Wf + 16384;
  const ushort_t* WVf = Wf + 32768;
  const f32x16 Z = {0,0,0,0,0,0,0,0,0,0,0,0,0,0,0,0};

  f32x16 sq = Z, sk = Z, sv = Z;
#pragma unroll
  for (int kc = 0; kc < 8; ++kc) {
    const size_t wo = (size_t)(dt * 8 + kc) * 512 + lane * 8;
    bf16x8 wq = *(const bf16x8*)(WQf + wo);
    bf16x8 wk = *(const bf16x8*)(WKf + wo);
    bf16x8 wvv = *(const bf16x8*)(WVf + wo);
    sq = MFMA32(wq, xf[kc], sq);     // D[m=d][n=pix]
    sk = MFMA32(wk, xf[kc], sk);
    sv = MFMA32(xf[kc], wvv, sv);    // D[m=pix][n=d]
  }

  // ---- Q/K stores (fragment-linear) ----
#pragma unroll
  for (int q = 0; q < 4; ++q) {
    const int dbase = dt * 32 + q * 8 + lq1 * 4;
    f32x4 b4q = *(const f32x4*)(bq + dbase);
    f32x4 b4k = *(const f32x4*)(bk + dbase);
    uint2 qs, ks;
    qs.x = pack2bf(sq[4*q+0] + b4q.x * LOG2E, sq[4*q+1] + b4q.y * LOG2E);
    qs.y = pack2bf(sq[4*q+2] + b4q.z * LOG2E, sq[4*q+3] + b4q.w * LOG2E);
    ks.x = pack2bf(sk[4*q+0] + b4k.x, sk[4*q+1] + b4k.y);
    ks.y = pack2bf(sk[4*q+2] + b4k.z, sk[4*q+3] + b4k.w);
    const int kcf = dt * 2 + (q >> 1), h = q & 1;
    const size_t off = ((size_t)((b * 128 + nt) * 8 + kcf) * 64 + h * 32 + l31) * 8 + lq1 * 4;
    *(uint2*)(Qf + off) = qs;
    *(uint2*)(Kf + off) = ks;
  }

  // ---- V stores ----
  {
    const float bvl = bv[dt * 32 + l31];           // lane = d
    const int j64 = nt >> 1, qp = nt & 1;
#pragma unroll
    for (int q = 0; q < 4; ++q) {
      uint2 vs;
      vs.x = pack2bf(sv[4*q+0] + bvl, sv[4*q+1] + bvl);
      vs.y = pack2bf(sv[4*q+2] + bvl, sv[4*q+3] + bvl);
      const int cc = qp * 2 + (q >> 1);
      const size_t off = ((size_t)((b * 64 + j64) * 4 + dt) * 4 + cc) * 512 +
                         (size_t)((q & 1) * 32 + l31) * 8 + lq1 * 4;
      *(uint2*)(Vf + off) = vs;
    }
  }
}

// ---------------------------------------------------------------------------
// Flash attention, FINAL = R19 (session-best total: 165.8us).
// R13 loop (3-buffer, per-tile counted vmcnt(4), symmetric staging, setprio,
// permlane softmax) at js=2 (one opart slice, WRITE 33MB, cheapest combine).
// Structural plateau documented: MFMA issue rate pinned ~0.044/CU-cyc across
// 8 falsified structural theories (pipeline, counted-vmcnt depth, no-LDS,
// pipe-split, 2x intensity, chain-split, 8-wave choreography, fused merge);
// escaping needs the full co-designed multi-phase rewrite (grafts regress).
// ---------------------------------------------------------------------------
__global__ __launch_bounds__(256, 3)
void flash_kernel(const ushort_t* __restrict__ Qf, const ushort_t* __restrict__ Kf,
                  const ushort_t* __restrict__ Vf, float* __restrict__ out,
                  float* __restrict__ opart, float* __restrict__ lpart, int js)
{
  const int b     = blockIdx.x & 7;
  const int itile = (blockIdx.x >> 3) & 31;
  const int jsl   = blockIdx.x >> 8;
  const int t     = threadIdx.x;
  const int wv    = t >> 6;
  const int lane  = t & 63;
  const int l31   = t & 31;
  const int lq1   = (t >> 5) & 1;
  const int i0    = itile * 128 + wv * 32;

  __shared__ __align__(16) short smem[24576];   // 48 KB: 3xK(8KB) + 3xV(8KB)

  const int jt0 = (jsl * 128) / js;
  const int jt1 = ((jsl + 1) * 128) / js;
  const int NT  = jt1 - jt0;
  const ushort_t* Kt0   = Kf + (size_t)b * 524288;
  const ushort_t* Vbase = Vf + (size_t)b * 524288;

  // Stage K(jt)+V(jt) into buffer p. Every wave: 2 K-chunks + 2 V-chunks
  // (4 x 1KB DMA) -> uniform vmcnt accounting across waves.
  auto stage = [&](int jt, int p) {
    ushort_t* kb = (ushort_t*)smem + p * 4096;
    ushort_t* vb = (ushort_t*)smem + 12288 + p * 4096;
    const ushort_t* ksrc = Kt0 + (size_t)jt * 4096;
    const int qp = jt & 1;
    const ushort_t* vsrc = Vbase + (size_t)(jt >> 1) * 8192;
#pragma unroll
    for (int c = 0; c < 2; ++c) {
      const int g = wv * 2 + c;
      gload_lds16(ksrc + g * 512 + lane * 8, kb + g * 512);
    }
#pragma unroll
    for (int c = 0; c < 2; ++c) {
      const int h2 = wv * 2 + c;
      const int ct = h2 >> 1, h = h2 & 1;
      gload_lds16(vsrc + (size_t)(ct * 4 + qp * 2 + h) * 512 + lane * 8,
                  vb + h2 * 512);
    }
  };

  // Q fragments (persistent, coalesced): i32-group = itile*4 + wv
  bf16x8 qf[8];
  const size_t qb = (size_t)((b * 128 + itile * 4 + wv) * 8) * 512;
#pragma unroll
  for (int kc = 0; kc < 8; ++kc)
    qf[kc] = *(const bf16x8*)(Qf + qb + (size_t)kc * 512 + lane * 8);

  const f32x16 Z = {0,0,0,0,0,0,0,0,0,0,0,0,0,0,0,0};
  f32x16 o[4] = {Z, Z, Z, Z};
  float lsum = 0.f;

  auto qk = [&](const short* kbuf) -> f32x16 {
    f32x16 s = Z;
#pragma unroll
    for (int kc = 0; kc < 8; ++kc) {
      bf16x8 kfr = *(const bf16x8*)&kbuf[kc * 512 + lane * 8];
      s = MFMA32(kfr, qf[kc], s);
    }
    return s;
  };
  auto pv = [&](const short* vbuf, bf16x8 a0, bf16x8 a1) {
#pragma unroll
    for (int ct = 0; ct < 4; ++ct) {
      bf16x8 vf0 = *(const bf16x8*)&vbuf[(ct * 2 + 0) * 512 + lane * 8];
      o[ct] = MFMA32(vf0, a0, o[ct]);
      bf16x8 vf1 = *(const bf16x8*)&vbuf[(ct * 2 + 1) * 512 + lane * 8];
      o[ct] = MFMA32(vf1, a1, o[ct]);
    }
  };

  // ---- prologue: tiles 0,1 in flight; wait only tile 0 (vmcnt(4)) ----
  stage(jt0, 0);
  stage(jt0 + 1, 1);
  asm volatile("s_waitcnt vmcnt(4)" ::: "memory");   // qf + tile0 done; tile1 in flight
  __builtin_amdgcn_sched_barrier(0);
  __builtin_amdgcn_s_barrier();
  __builtin_amdgcn_sched_barrier(0);

  int pcur = 0, pstage = 2;
  for (int n = 0; n < NT; ++n) {
    if (n + 2 < NT) stage(jt0 + n + 2, pstage);      // into buf holding tile n-1
    pstage = (pstage == 2) ? 0 : pstage + 1;
    const short* kb = smem + pcur * 4096;
    const short* vb = smem + 12288 + pcur * 4096;
    pcur = (pcur == 2) ? 0 : pcur + 1;

    __builtin_amdgcn_s_setprio(1);
    f32x16 s = qk(kb);                               // S^T(n) = K*Q
    __builtin_amdgcn_s_setprio(0);
    bf16x8 pa0 = mk_pa(s, 0, lsum);                  // softmax (exp2 domain)
    bf16x8 pa1 = mk_pa(s, 8, lsum);
    __builtin_amdgcn_s_setprio(1);
    pv(vb, pa0, pa1);                                // PV(n)
    __builtin_amdgcn_s_setprio(0);

    if (n + 1 < NT) {
      if (n + 2 < NT) asm volatile("s_waitcnt vmcnt(4)" ::: "memory");  // tile n+1 ready
      else            asm volatile("s_waitcnt vmcnt(0)" ::: "memory");  // tail
      __builtin_amdgcn_sched_barrier(0);
      __builtin_amdgcn_s_barrier();
      __builtin_amdgcn_sched_barrier(0);
    }
  }

  lsum += __shfl_xor(lsum, 32);   // full row sum; lane l31 -> i = i0 + l31
  const int ib = i0 + l31;

  if (js == 1) {
    const float inv = 1.0f / lsum;
#pragma unroll
    for (int ct = 0; ct < 4; ++ct)
#pragma unroll
      for (int rg = 0; rg < 16; ++rg) {
        const int c = ct * 32 + (rg >> 2) * 8 + lq1 * 4 + (rg & 3);
        out[(size_t)(b * C_ + c) * N_ + ib] = o[ct][rg] * inv;
      }
  } else {
    float* op = jsl ? (opart + (size_t)(jsl - 1) * B_ * C_ * N_) : out;
#pragma unroll
    for (int ct = 0; ct < 4; ++ct)
#pragma unroll
      for (int rg = 0; rg < 16; ++rg) {
        const int c = ct * 32 + (rg >> 2) * 8 + lq1 * 4 + (rg & 3);
        op[(size_t)(b * C_ + c) * N_ + ib] = o[ct][rg];
      }
    if (lane < 32)
      lpart[(size_t)jsl * B_ * N_ + (size_t)b * N_ + ib] = lsum;
  }
}

// ---------------------------------------------------------------------------
// Combine: slice 0 lives in `out` (aliased); sums + normalizes in place.
// ---------------------------------------------------------------------------
__global__ __launch_bounds__(256)
void combine_kernel(const float* __restrict__ opart, const float* __restrict__ lpart,
                    float* __restrict__ out, int js)
{
  const int t  = blockIdx.x * 256 + threadIdx.x;
  const int n4 = (t & 1023) * 4;
  const int bc = t >> 10;
  const int b  = bc >> 7;
  const size_t off  = (size_t)bc * N_ + n4;
  const size_t loff = (size_t)b * N_ + n4;
  f32x4 os = *(const f32x4*)(out + off);
  f32x4 ls = *(const f32x4*)(lpart + loff);
  for (int s = 1; s < js; ++s) {
    os += *(const f32x4*)(opart + (size_t)(s - 1) * B_ * C_ * N_ + off);
    ls += *(const f32x4*)(lpart + (size_t)s * B_ * N_ + loff);
  }
  f32x4 r = { os.x / ls.x, os.y / ls.y, os.z / ls.z, os.w / ls.w };
  *(f32x4*)(out + off) = r;
}

// ---------------------------------------------------------------------------
extern "C" void kernel_launch(void* const* d_in, const int* in_sizes, int n_in,
                              void* d_out, int out_size, void* d_ws, size_t ws_size,
                              hipStream_t stream) {
  const float* x  = (const float*)d_in[0];
  const float* Wq = (const float*)d_in[1];
  const float* bq = (const float*)d_in[2];
  const float* Wk = (const float*)d_in[3];
  const float* bk = (const float*)d_in[4];
  const float* Wv = (const float*)d_in[5];
  const float* bv = (const float*)d_in[6];
  float* out = (float*)d_out;

  const size_t nc = (size_t)B_ * N_ * C_;
  ushort_t* qf = (ushort_t*)d_ws;
  ushort_t* kf = qf + nc;
  ushort_t* vf = kf + nc;
  ushort_t* wf = vf + nc;                          // 49152 elems
  const size_t base = (3 * nc + 49152) * sizeof(ushort_t);

  auto need = [&](int jss) {
    return base + (size_t)jss * (size_t)B_ * N_ * 4 +
           (size_t)(jss - 1) * (size_t)B_ * C_ * N_ * 4;   // slice0 = d_out
  };
  // js=2 (proven best slice count: one opart slice, WRITE 33MB).
  const int js = (ws_size >= need(2)) ? 2 : 1;

  float* lpart = (float*)((char*)d_ws + base);
  float* opart = lpart + (size_t)js * B_ * N_;

  hipLaunchKernelGGL(wprep_kernel, dim3(24), dim3(256), 0, stream, Wq, Wk, Wv, wf);
  hipLaunchKernelGGL(proj_kernel, dim3(1024), dim3(256), 0, stream,
                     x, bq, bk, bv, wf, qf, kf, vf);
  hipLaunchKernelGGL(flash_kernel, dim3(256 * js), dim3(256), 0, stream,
                     qf, kf, vf, out, opart, lpart, js);
  if (js > 1)
    hipLaunchKernelGGL(combine_kernel, dim3(4096), dim3(256), 0, stream,
                       opart, lpart, out, js);
}